// Round 2
// baseline (202.521 us; speedup 1.0000x reference)
//
#include <hip/hip_runtime.h>
#include <hip/hip_cooperative_groups.h>

namespace cg = cooperative_groups;

#define S_ 512
#define D_ 768
#define NH 12
#define HD 64
#define RK 16
#define D3 2304
#define LN_EPS 1e-5f

// odd Taylor tanh coefficients (deg-5; |d|<~0.35)
#define C3B (-0.3333333433f)
#define C5B (0.1333333403f)

typedef __attribute__((ext_vector_type(8))) short bfrag;
typedef __attribute__((ext_vector_type(4))) float ffrag;

__device__ __forceinline__ unsigned short f2bf(float f) {
    unsigned int u = __float_as_uint(f);
    unsigned int r = (u + 0x7FFFu + ((u >> 16) & 1u)) >> 16;   // RNE
    return (unsigned short)r;
}

// Pade [3/4] tanh for g_val (|x|<=0.02)
__device__ __forceinline__ float fast_tanh(float x) {
    float x2 = x * x;
    float num = x * __fmaf_rn(x2, 10.f, 105.f);
    float den = __fmaf_rn(x2 + 45.f, x2, 105.f);
    return num * __builtin_amdgcn_rcpf(den);
}

// ---------------- single cooperative mega-kernel ---------------------------
// Phase A: blocks [0,128)   : LayerNorm + h = silu(xn @ W1^T), one wave/row
//          blocks [128,256) : Wv -> bf16 pack
// grid.sync()
// Phase B: 288 amix units strided over 256 blocks (K=16 GEMM + L/R/J/I/Avb)
// grid.sync()
// Phase C: 768 mm units + 96 delta units strided over 256 blocks
__global__ __launch_bounds__(256, 2) void k_mega(
    const float* __restrict__ x, const float* __restrict__ gamma,
    const float* __restrict__ beta, const float* __restrict__ W1,
    const float* __restrict__ Wv,
    const float* __restrict__ W2, const float* __restrict__ Wq,
    const float* __restrict__ Wk, const float* __restrict__ g_attn,
    const float* __restrict__ qb, const float* __restrict__ kb,
    const float* __restrict__ relb, const float* __restrict__ g_rel,
    const float* __restrict__ g_val,
    unsigned short* __restrict__ Wvb, float* __restrict__ hout,
    unsigned short* __restrict__ Avb,
    unsigned short* __restrict__ L, unsigned short* __restrict__ R,
    float* __restrict__ J, float* __restrict__ I,
    float* __restrict__ dv, float* __restrict__ gauge)
{
    __shared__ float hs[64 * 17];
    __shared__ float w2s[64 * 17];
    __shared__ float At[64 * 68];    // [s][dd]
    __shared__ float Ws[64 * 68];    // [dd][i] transposed

    const int bid = blockIdx.x;
    const int t = threadIdx.x;

    // ================= Phase A =================
    if (bid < 128) {
        const int row = bid * 4 + (t >> 6);
        const int lane = t & 63;
        const float4* xr = (const float4*)(x + (size_t)row * D_);
        float4 a = xr[lane], b = xr[lane + 64], c = xr[lane + 128];
        float s = a.x + a.y + a.z + a.w + b.x + b.y + b.z + b.w + c.x + c.y + c.z + c.w;
        float sq = a.x*a.x + a.y*a.y + a.z*a.z + a.w*a.w
                 + b.x*b.x + b.y*b.y + b.z*b.z + b.w*b.w
                 + c.x*c.x + c.y*c.y + c.z*c.z + c.w*c.w;
        #pragma unroll
        for (int m = 1; m < 64; m <<= 1) { s += __shfl_xor(s, m); sq += __shfl_xor(sq, m); }
        float mean = s * (1.f / D_);
        float rstd = rsqrtf(sq * (1.f / D_) - mean * mean + LN_EPS);
        const float4* g4 = (const float4*)gamma;
        const float4* b4 = (const float4*)beta;
        float4 ga_ = g4[lane], gb_ = g4[lane + 64], gc_ = g4[lane + 128];
        float4 ba_ = b4[lane], bb_ = b4[lane + 64], bc_ = b4[lane + 128];
        float4 na, nb, nc;
        na.x = (a.x-mean)*rstd*ga_.x + ba_.x; na.y = (a.y-mean)*rstd*ga_.y + ba_.y;
        na.z = (a.z-mean)*rstd*ga_.z + ba_.z; na.w = (a.w-mean)*rstd*ga_.w + ba_.w;
        nb.x = (b.x-mean)*rstd*gb_.x + bb_.x; nb.y = (b.y-mean)*rstd*gb_.y + bb_.y;
        nb.z = (b.z-mean)*rstd*gb_.z + bb_.z; nb.w = (b.w-mean)*rstd*gb_.w + bb_.w;
        nc.x = (c.x-mean)*rstd*gc_.x + bc_.x; nc.y = (c.y-mean)*rstd*gc_.y + bc_.y;
        nc.z = (c.z-mean)*rstd*gc_.z + bc_.z; nc.w = (c.w-mean)*rstd*gc_.w + bc_.w;

        float hval = 0.f;
        #pragma unroll
        for (int r = 0; r < RK; ++r) {
            const float4* wr = (const float4*)(W1 + (size_t)r * D_);
            float4 wa = wr[lane], wb = wr[lane + 64], wc = wr[lane + 128];
            float p = na.x*wa.x + na.y*wa.y + na.z*wa.z + na.w*wa.w
                    + nb.x*wb.x + nb.y*wb.y + nb.z*wb.z + nb.w*wb.w
                    + nc.x*wc.x + nc.y*wc.y + nc.z*wc.z + nc.w*wc.w;
            #pragma unroll
            for (int m = 1; m < 64; m <<= 1) p += __shfl_xor(p, m);
            if (lane == r) hval = p;
        }
        if (lane < RK)
            hout[row * RK + lane] = hval * __builtin_amdgcn_rcpf(1.f + __expf(-hval));
    } else {
        // Wv -> bf16 pack: 589824 elems / 32768 threads = 18 each
        const int gid = (bid - 128) * 256 + t;
        #pragma unroll
        for (int l = 0; l < 18; ++l)
            Wvb[gid + 32768 * l] = f2bf(Wv[gid + 32768 * l]);
    }

    cg::this_grid().sync();

    // ================= Phase B: amix units =================
    const int tx = t & 15, ty = t >> 4;
    for (int bu = bid; bu < 288; bu += 256) {
        int s0, c0, which = 0, hh = 0;
        bool qk = (bu < 192);
        if (qk) { which = bu & 1; hh = (bu >> 1) % NH; s0 = ((bu >> 1) / NH) * 64; c0 = which * D_ + hh * HD; }
        else    { int b2 = bu - 192; s0 = (b2 / NH) * 64; hh = b2 % NH; c0 = 1536 + hh * HD; }

        {
            int r = t >> 2, q = (t & 3) * 4;
            float4 hv = *(const float4*)(hout + (size_t)(s0 + r) * RK + q);
            hs[r*17+q] = hv.x; hs[r*17+q+1] = hv.y; hs[r*17+q+2] = hv.z; hs[r*17+q+3] = hv.w;
            float4 wv = *(const float4*)(W2 + (size_t)(c0 + r) * RK + q);
            w2s[r*17+q] = wv.x; w2s[r*17+q+1] = wv.y; w2s[r*17+q+2] = wv.z; w2s[r*17+q+3] = wv.w;
        }
        if (qk) {
            const float* Wsrc = which ? Wk : Wq;
            #pragma unroll
            for (int l = 0; l < 4; ++l) {
                int m = t + 256 * l;
                int i = m >> 4, dq = (m & 15) * 4;
                float4 wv = *(const float4*)(Wsrc + (size_t)i * HD + dq);
                Ws[(dq+0)*68+i] = wv.x; Ws[(dq+1)*68+i] = wv.y;
                Ws[(dq+2)*68+i] = wv.z; Ws[(dq+3)*68+i] = wv.w;
            }
        }
        __syncthreads();

        float acc[4][4] = {};
        #pragma unroll
        for (int k = 0; k < RK; ++k) {
            float a0 = hs[(4*ty+0)*17+k], a1 = hs[(4*ty+1)*17+k];
            float a2 = hs[(4*ty+2)*17+k], a3 = hs[(4*ty+3)*17+k];
            float w0 = w2s[(4*tx+0)*17+k], w1 = w2s[(4*tx+1)*17+k];
            float w2v = w2s[(4*tx+2)*17+k], w3 = w2s[(4*tx+3)*17+k];
            acc[0][0]=__fmaf_rn(a0,w0,acc[0][0]); acc[0][1]=__fmaf_rn(a0,w1,acc[0][1]);
            acc[0][2]=__fmaf_rn(a0,w2v,acc[0][2]); acc[0][3]=__fmaf_rn(a0,w3,acc[0][3]);
            acc[1][0]=__fmaf_rn(a1,w0,acc[1][0]); acc[1][1]=__fmaf_rn(a1,w1,acc[1][1]);
            acc[1][2]=__fmaf_rn(a1,w2v,acc[1][2]); acc[1][3]=__fmaf_rn(a1,w3,acc[1][3]);
            acc[2][0]=__fmaf_rn(a2,w0,acc[2][0]); acc[2][1]=__fmaf_rn(a2,w1,acc[2][1]);
            acc[2][2]=__fmaf_rn(a2,w2v,acc[2][2]); acc[2][3]=__fmaf_rn(a2,w3,acc[2][3]);
            acc[3][0]=__fmaf_rn(a3,w0,acc[3][0]); acc[3][1]=__fmaf_rn(a3,w1,acc[3][1]);
            acc[3][2]=__fmaf_rn(a3,w2v,acc[3][2]); acc[3][3]=__fmaf_rn(a3,w3,acc[3][3]);
        }

        if (!qk) {   // value field -> bf16 Avb
            #pragma unroll
            for (int i = 0; i < 4; ++i) {
                ushort4 v = make_ushort4(f2bf(acc[i][0]), f2bf(acc[i][1]),
                                         f2bf(acc[i][2]), f2bf(acc[i][3]));
                *(ushort4*)(Avb + (size_t)(s0 + 4*ty + i) * D_ + hh * HD + 4*tx) = v;
            }
        } else {
            // stash A values for the projection phase
            #pragma unroll
            for (int i = 0; i < 4; ++i)
                *(float4*)(At + (4*ty + i) * 68 + 4*tx) =
                    make_float4(acc[i][0], acc[i][1], acc[i][2], acc[i][3]);

            // raw base copy (q->L[0:64) or k->R[64:128)) — no LDS dependency
            {
                unsigned short* P = which ? R : L;
                const float* src = which ? kb : qb;
                const int segb = which ? 64 : 0;
                int r = t >> 2, cq = (t & 3) * 16;
                const float* sp = src + ((size_t)(hh * S_ + s0 + r)) * HD + cq;
                unsigned short* dp = P + ((size_t)(hh * S_ + s0 + r)) * 384 + segb + cq;
                #pragma unroll
                for (int u = 0; u < 4; ++u) {
                    float4 v = *(const float4*)(sp + 4*u);
                    *(ushort4*)(dp + 4*u) = make_ushort4(f2bf(v.x), f2bf(v.y), f2bf(v.z), f2bf(v.w));
                }
            }

            // per-dd weights w = relb * g_rel for this head
            float w_[4];
            {
                float grv = g_rel[hh];
                float4 rb4 = *(const float4*)(relb + hh * HD + 4*tx);
                w_[0] = rb4.x * grv; w_[1] = rb4.y * grv; w_[2] = rb4.z * grv; w_[3] = rb4.w * grv;
            }

            // power/poly segments + row-reduction partials
            float red[4];
            #pragma unroll
            for (int i = 0; i < 4; ++i) {
                size_t rb = ((size_t)(hh * S_ + s0 + 4*ty + i)) * 384;
                float partial = 0.f;
                ushort4 o1, o2, o3, o4;
                if (which == 0) {
                    #pragma unroll
                    for (int j = 0; j < 4; ++j) {
                        float xv = acc[i][j];
                        float x2 = xv*xv, x3 = x2*xv, x4 = x2*x2, x5 = x3*x2;
                        ((unsigned short*)&o1)[j] = f2bf(xv);
                        ((unsigned short*)&o2)[j] = f2bf(x2);
                        ((unsigned short*)&o3)[j] = f2bf(x3);
                        ((unsigned short*)&o4)[j] = f2bf(x4);
                        partial += w_[j] * x5;
                    }
                    *(ushort4*)(L + rb + 128 + 4*tx) = o1;
                    *(ushort4*)(L + rb + 192 + 4*tx) = o2;
                    *(ushort4*)(L + rb + 256 + 4*tx) = o3;
                    *(ushort4*)(L + rb + 320 + 4*tx) = o4;
                } else {
                    #pragma unroll
                    for (int j = 0; j < 4; ++j) {
                        float bv = acc[i][j];
                        float b2 = bv*bv, b3 = b2*bv, b4 = b2*b2, b5 = b3*b2;
                        float w = w_[j];
                        ((unsigned short*)&o1)[j] = f2bf(w * (-1.f - 3.f*C3B*b2 - 5.f*C5B*b4));
                        ((unsigned short*)&o2)[j] = f2bf(w * (3.f*C3B*bv + 10.f*C5B*b3));
                        ((unsigned short*)&o3)[j] = f2bf(w * (-C3B - 10.f*C5B*b2));
                        ((unsigned short*)&o4)[j] = f2bf(w * (5.f*C5B*bv));
                        partial += w * (bv + C3B*b3 + C5B*b5);
                    }
                    *(ushort4*)(R + rb + 128 + 4*tx) = o1;
                    *(ushort4*)(R + rb + 192 + 4*tx) = o2;
                    *(ushort4*)(R + rb + 256 + 4*tx) = o3;
                    *(ushort4*)(R + rb + 320 + 4*tx) = o4;
                }
                red[i] = partial;
            }
            #pragma unroll
            for (int mm = 1; mm < 16; mm <<= 1) {
                #pragma unroll
                for (int i = 0; i < 4; ++i) red[i] += __shfl_xor(red[i], mm);
            }
            if (tx == 0) {
                #pragma unroll
                for (int i = 0; i < 4; ++i) {
                    int row = hh * S_ + s0 + 4*ty + i;
                    if (which == 0) I[row] = -C5B * red[i];
                    else            J[row] = red[i];
                }
            }
            __syncthreads();

            // projection: pacc[s][i] = sum_dd At[s][dd] * W[i][dd]  (then * 0.125*g_attn)
            float pacc[4][4] = {};
            #pragma unroll 8
            for (int dd = 0; dd < HD; ++dd) {
                float a0 = At[(4*ty+0)*68+dd], a1 = At[(4*ty+1)*68+dd];
                float a2 = At[(4*ty+2)*68+dd], a3 = At[(4*ty+3)*68+dd];
                float4 wv = *(const float4*)(Ws + dd*68 + 4*tx);
                pacc[0][0]=__fmaf_rn(a0,wv.x,pacc[0][0]); pacc[0][1]=__fmaf_rn(a0,wv.y,pacc[0][1]);
                pacc[0][2]=__fmaf_rn(a0,wv.z,pacc[0][2]); pacc[0][3]=__fmaf_rn(a0,wv.w,pacc[0][3]);
                pacc[1][0]=__fmaf_rn(a1,wv.x,pacc[1][0]); pacc[1][1]=__fmaf_rn(a1,wv.y,pacc[1][1]);
                pacc[1][2]=__fmaf_rn(a1,wv.z,pacc[1][2]); pacc[1][3]=__fmaf_rn(a1,wv.w,pacc[1][3]);
                pacc[2][0]=__fmaf_rn(a2,wv.x,pacc[2][0]); pacc[2][1]=__fmaf_rn(a2,wv.y,pacc[2][1]);
                pacc[2][2]=__fmaf_rn(a2,wv.z,pacc[2][2]); pacc[2][3]=__fmaf_rn(a2,wv.w,pacc[2][3]);
                pacc[3][0]=__fmaf_rn(a3,wv.x,pacc[3][0]); pacc[3][1]=__fmaf_rn(a3,wv.y,pacc[3][1]);
                pacc[3][2]=__fmaf_rn(a3,wv.z,pacc[3][2]); pacc[3][3]=__fmaf_rn(a3,wv.w,pacc[3][3]);
            }
            float sc = 0.125f * g_attn[hh];
            #pragma unroll
            for (int i = 0; i < 4; ++i) {
                size_t rb = ((size_t)(hh * S_ + s0 + 4*ty + i)) * 384;
                ushort4 o = make_ushort4(f2bf(pacc[i][0]*sc), f2bf(pacc[i][1]*sc),
                                         f2bf(pacc[i][2]*sc), f2bf(pacc[i][3]*sc));
                unsigned short* dst = which ? (R + rb + 4*tx) : (L + rb + 64 + 4*tx);
                *(ushort4*)dst = o;
            }
        }
        __syncthreads();   // protect LDS for next strided unit
    }

    cg::this_grid().sync();

    // ================= Phase C: 768 mm units + 96 delta units =================
    const int wave = t >> 6, lane = t & 63;
    const int wy = wave >> 1, wx = wave & 1;
    const int m = lane & 15, q = lane >> 4;

    for (int u = bid; u < 864; u += 256) {
        if (u < 768) {
            // ---- gauge = L @ R^T (K=384) + J[j] + I[i] ----
            const int h = u >> 6;
            const int rem = u & 63;
            const int i0 = (rem >> 3) * 64, j0 = (rem & 7) * 64;
            const int ib = i0 + wy * 32, jb = j0 + wx * 32;

            const unsigned short* pa0 = L + ((size_t)(h * S_) + ib + m) * 384 + 8 * q;
            const unsigned short* pa1 = pa0 + 16 * 384;
            const unsigned short* pb0 = R + ((size_t)(h * S_) + jb + m) * 384 + 8 * q;
            const unsigned short* pb1 = pb0 + 16 * 384;

            ffrag acc00 = {0.f,0.f,0.f,0.f}, acc01 = acc00, acc10 = acc00, acc11 = acc00;
            #pragma unroll
            for (int kc = 0; kc < 12; ++kc) {
                bfrag a0 = *(const bfrag*)(pa0 + kc * 32);
                bfrag a1 = *(const bfrag*)(pa1 + kc * 32);
                bfrag b0 = *(const bfrag*)(pb0 + kc * 32);
                bfrag b1 = *(const bfrag*)(pb1 + kc * 32);
                acc00 = __builtin_amdgcn_mfma_f32_16x16x32_bf16(a0, b0, acc00, 0, 0, 0);
                acc01 = __builtin_amdgcn_mfma_f32_16x16x32_bf16(a0, b1, acc01, 0, 0, 0);
                acc10 = __builtin_amdgcn_mfma_f32_16x16x32_bf16(a1, b0, acc10, 0, 0, 0);
                acc11 = __builtin_amdgcn_mfma_f32_16x16x32_bf16(a1, b1, acc11, 0, 0, 0);
            }

            const float Jc0 = J[h * S_ + jb + m];
            const float Jc1 = J[h * S_ + jb + 16 + m];
            float* ob = gauge + ((size_t)h * S_) * S_;
            #pragma unroll
            for (int reg = 0; reg < 4; ++reg) {
                int r0 = ib + 4 * q + reg, r1 = r0 + 16;
                float i0v = I[h * S_ + r0];
                ob[(size_t)r0 * S_ + jb + m]      = acc00[reg] + Jc0 + i0v;
                ob[(size_t)r0 * S_ + jb + 16 + m] = acc01[reg] + Jc1 + i0v;
                float i1v = I[h * S_ + r1];
                ob[(size_t)r1 * S_ + jb + m]      = acc10[reg] + Jc0 + i1v;
                ob[(size_t)r1 * S_ + jb + 16 + m] = acc11[reg] + Jc1 + i1v;
            }
        } else {
            // ---- dv = tanh(g_val) * (Avb @ Wvb^T), full K=768 ----
            const int d = u - 768;
            const int e0 = (d % 12) * 64, s0 = (d / 12) * 64;
            const int sb = s0 + wy * 32, eb = e0 + wx * 32;

            const unsigned short* pa0 = Avb + (size_t)(sb + m) * D_ + 8 * q;
            const unsigned short* pa1 = pa0 + 16 * D_;
            const unsigned short* pb0 = Wvb + (size_t)(eb + m) * D_ + 8 * q;
            const unsigned short* pb1 = pb0 + 16 * D_;

            ffrag acc00 = {0.f,0.f,0.f,0.f}, acc01 = acc00, acc10 = acc00, acc11 = acc00;
            #pragma unroll 8
            for (int kc = 0; kc < 24; ++kc) {
                bfrag a0 = *(const bfrag*)(pa0 + kc * 32);
                bfrag a1 = *(const bfrag*)(pa1 + kc * 32);
                bfrag b0 = *(const bfrag*)(pb0 + kc * 32);
                bfrag b1 = *(const bfrag*)(pb1 + kc * 32);
                acc00 = __builtin_amdgcn_mfma_f32_16x16x32_bf16(a0, b0, acc00, 0, 0, 0);
                acc01 = __builtin_amdgcn_mfma_f32_16x16x32_bf16(a0, b1, acc01, 0, 0, 0);
                acc10 = __builtin_amdgcn_mfma_f32_16x16x32_bf16(a1, b0, acc10, 0, 0, 0);
                acc11 = __builtin_amdgcn_mfma_f32_16x16x32_bf16(a1, b1, acc11, 0, 0, 0);
            }

            const float t0 = fast_tanh(g_val[eb + m]);
            const float t1 = fast_tanh(g_val[eb + 16 + m]);
            #pragma unroll
            for (int reg = 0; reg < 4; ++reg) {
                int r0 = sb + 4 * q + reg, r1 = r0 + 16;
                dv[(size_t)r0 * D_ + eb + m]      = acc00[reg] * t0;
                dv[(size_t)r0 * D_ + eb + 16 + m] = acc01[reg] * t1;
                dv[(size_t)r1 * D_ + eb + m]      = acc10[reg] * t0;
                dv[(size_t)r1 * D_ + eb + 16 + m] = acc11[reg] * t1;
            }
        }
    }
}

extern "C" void kernel_launch(void* const* d_in, const int* in_sizes, int n_in,
                              void* d_out, int out_size, void* d_ws, size_t ws_size,
                              hipStream_t stream)
{
    (void)in_sizes; (void)n_in; (void)out_size; (void)ws_size;
    const float* hs   = (const float*)d_in[0];
    const float* qb   = (const float*)d_in[1];
    const float* kb   = (const float*)d_in[2];
    const float* gam  = (const float*)d_in[3];
    const float* bet  = (const float*)d_in[4];
    const float* W1   = (const float*)d_in[5];
    const float* W2   = (const float*)d_in[6];
    const float* Wq   = (const float*)d_in[7];
    const float* Wk   = (const float*)d_in[8];
    const float* Wv   = (const float*)d_in[9];
    const float* relb = (const float*)d_in[10];
    const float* ga   = (const float*)d_in[11];
    const float* gr   = (const float*)d_in[12];
    const float* gv   = (const float*)d_in[13];

    // ws layout
    unsigned short* Avb = (unsigned short*)d_ws;              // 512*768
    unsigned short* Wvb = Avb + (size_t)S_ * D_;              // 768*768
    unsigned short* Lb  = Wvb + (size_t)D_ * D_;              // 12*512*384
    unsigned short* Rb  = Lb + (size_t)NH * S_ * 384;         // 12*512*384
    float* Jv   = (float*)(Rb + (size_t)NH * S_ * 384);       // 12*512
    float* Iv   = Jv + NH * S_;                               // 12*512

    float* gauge = (float*)d_out;                             // 12*512*512
    float* dv   = gauge + (size_t)NH * S_ * S_;               // 512*768
    float* hbuf = dv;                                         // h in dv slot (dead until phase C)

    void* args[] = { (void*)&hs, (void*)&gam, (void*)&bet, (void*)&W1, (void*)&Wv,
                     (void*)&W2, (void*)&Wq, (void*)&Wk, (void*)&ga, (void*)&qb,
                     (void*)&kb, (void*)&relb, (void*)&gr, (void*)&gv,
                     (void*)&Wvb, (void*)&hbuf, (void*)&Avb, (void*)&Lb, (void*)&Rb,
                     (void*)&Jv, (void*)&Iv, (void*)&dv, (void*)&gauge };
    hipLaunchCooperativeKernel((void*)k_mega, dim3(256), dim3(256), args, 0, stream);
}

// Round 3
// 129.289 us; speedup vs baseline: 1.5664x; 1.5664x over previous
//
#include <hip/hip_runtime.h>

#define S_ 512
#define D_ 768
#define NH 12
#define HD 64
#define RK 16
#define D3 2304
#define LN_EPS 1e-5f

// odd Taylor tanh coefficients (deg-5; |d|<~0.35)
#define C3B (-0.3333333433f)
#define C5B (0.1333333403f)

typedef __attribute__((ext_vector_type(8))) short bfrag;
typedef __attribute__((ext_vector_type(4))) float ffrag;

__device__ __forceinline__ unsigned short f2bf(float f) {
    unsigned int u = __float_as_uint(f);
    unsigned int r = (u + 0x7FFFu + ((u >> 16) & 1u)) >> 16;   // RNE
    return (unsigned short)r;
}

// Pade [3/4] tanh for g_val (|x|<=0.02)
__device__ __forceinline__ float fast_tanh(float x) {
    float x2 = x * x;
    float num = x * __fmaf_rn(x2, 10.f, 105.f);
    float den = __fmaf_rn(x2 + 45.f, x2, 105.f);
    return num * __builtin_amdgcn_rcpf(den);
}

// ---------------- Kernel 1: LayerNorm + h = silu(xn @ W1^T), one wave/row;
// 512 blocks x 64 threads so all 256 CUs participate.
// Also packs Wv -> bf16 (independent side job). ----------------------------
__global__ __launch_bounds__(64) void k_ln(
    const float* __restrict__ x, const float* __restrict__ gamma,
    const float* __restrict__ beta, const float* __restrict__ W1,
    const float* __restrict__ Wv, unsigned short* __restrict__ Wvb,
    float* __restrict__ hout)
{
    const int row = blockIdx.x;
    const int lane = threadIdx.x;
    const float4* xr = (const float4*)(x + (size_t)row * D_);
    float4 a = xr[lane], b = xr[lane + 64], c = xr[lane + 128];
    float s = a.x + a.y + a.z + a.w + b.x + b.y + b.z + b.w + c.x + c.y + c.z + c.w;
    float sq = a.x*a.x + a.y*a.y + a.z*a.z + a.w*a.w
             + b.x*b.x + b.y*b.y + b.z*b.z + b.w*b.w
             + c.x*c.x + c.y*c.y + c.z*c.z + c.w*c.w;
    #pragma unroll
    for (int m = 1; m < 64; m <<= 1) { s += __shfl_xor(s, m); sq += __shfl_xor(sq, m); }
    float mean = s * (1.f / D_);
    float rstd = rsqrtf(sq * (1.f / D_) - mean * mean + LN_EPS);
    const float4* g4 = (const float4*)gamma;
    const float4* b4 = (const float4*)beta;
    float4 ga_ = g4[lane], gb_ = g4[lane + 64], gc_ = g4[lane + 128];
    float4 ba_ = b4[lane], bb_ = b4[lane + 64], bc_ = b4[lane + 128];
    float4 na, nb, nc;
    na.x = (a.x-mean)*rstd*ga_.x + ba_.x; na.y = (a.y-mean)*rstd*ga_.y + ba_.y;
    na.z = (a.z-mean)*rstd*ga_.z + ba_.z; na.w = (a.w-mean)*rstd*ga_.w + ba_.w;
    nb.x = (b.x-mean)*rstd*gb_.x + bb_.x; nb.y = (b.y-mean)*rstd*gb_.y + bb_.y;
    nb.z = (b.z-mean)*rstd*gb_.z + bb_.z; nb.w = (b.w-mean)*rstd*gb_.w + bb_.w;
    nc.x = (c.x-mean)*rstd*gc_.x + bc_.x; nc.y = (c.y-mean)*rstd*gc_.y + bc_.y;
    nc.z = (c.z-mean)*rstd*gc_.z + bc_.z; nc.w = (c.w-mean)*rstd*gc_.w + bc_.w;

    float hval = 0.f;
    #pragma unroll
    for (int r = 0; r < RK; ++r) {
        const float4* wr = (const float4*)(W1 + (size_t)r * D_);
        float4 wa = wr[lane], wb = wr[lane + 64], wc = wr[lane + 128];
        float p = na.x*wa.x + na.y*wa.y + na.z*wa.z + na.w*wa.w
                + nb.x*wb.x + nb.y*wb.y + nb.z*wb.z + nb.w*wb.w
                + nc.x*wc.x + nc.y*wc.y + nc.z*wc.z + nc.w*wc.w;
        #pragma unroll
        for (int m = 1; m < 64; m <<= 1) p += __shfl_xor(p, m);
        if (lane == r) hval = p;
    }
    if (lane < RK)
        hout[row * RK + lane] = hval * __builtin_amdgcn_rcpf(1.f + __expf(-hval));

    // Wv -> bf16 pack: 589824 elems / 32768 threads = 18 each
    const int gid = blockIdx.x * 64 + threadIdx.x;
    #pragma unroll
    for (int l = 0; l < 18; ++l)
        Wvb[gid + 32768 * l] = f2bf(Wv[gid + 32768 * l]);
}

// ---------------- Kernel 2: A-slice GEMM (K=16) fused with:
//  v-blocks : write bf16 Avb
//  q-blocks : L = [q | aqp'' | x | x^2 | x^3 | x^4], I[row] = -C5 sum w x^5
//  k-blocks : R = [akp'' | k | P1..P4],             J[row] = sum w(b+C3b^3+C5b^5)
__global__ __launch_bounds__(256) void k_amix(
    const float* __restrict__ h, const float* __restrict__ W2,
    const float* __restrict__ Wq, const float* __restrict__ Wk,
    const float* __restrict__ g_attn,
    const float* __restrict__ qb, const float* __restrict__ kb,
    const float* __restrict__ relb, const float* __restrict__ g_rel,
    unsigned short* __restrict__ Avb,
    unsigned short* __restrict__ L, unsigned short* __restrict__ R,
    float* __restrict__ J, float* __restrict__ I)
{
    __shared__ float hs[64 * 17];
    __shared__ float w2s[64 * 17];
    __shared__ float At[64 * 68];    // [s][dd]
    __shared__ float Ws[64 * 68];    // [dd][i] transposed
    const int b = blockIdx.x;
    const int t = threadIdx.x;
    const int tx = t & 15, ty = t >> 4;

    int s0, c0, which = 0, hh = 0;
    bool qk = (b < 192);
    if (qk) { which = b & 1; hh = (b >> 1) % NH; s0 = ((b >> 1) / NH) * 64; c0 = which * D_ + hh * HD; }
    else    { int b2 = b - 192; s0 = (b2 / NH) * 64; hh = b2 % NH; c0 = 1536 + hh * HD; }

    {
        int r = t >> 2, q = (t & 3) * 4;
        float4 hv = *(const float4*)(h + (size_t)(s0 + r) * RK + q);
        hs[r*17+q] = hv.x; hs[r*17+q+1] = hv.y; hs[r*17+q+2] = hv.z; hs[r*17+q+3] = hv.w;
        float4 wv = *(const float4*)(W2 + (size_t)(c0 + r) * RK + q);
        w2s[r*17+q] = wv.x; w2s[r*17+q+1] = wv.y; w2s[r*17+q+2] = wv.z; w2s[r*17+q+3] = wv.w;
    }
    if (qk) {
        const float* Wsrc = which ? Wk : Wq;
        #pragma unroll
        for (int l = 0; l < 4; ++l) {
            int m = t + 256 * l;
            int i = m >> 4, dq = (m & 15) * 4;
            float4 wv = *(const float4*)(Wsrc + (size_t)i * HD + dq);
            Ws[(dq+0)*68+i] = wv.x; Ws[(dq+1)*68+i] = wv.y;
            Ws[(dq+2)*68+i] = wv.z; Ws[(dq+3)*68+i] = wv.w;
        }
    }
    __syncthreads();

    float acc[4][4] = {};
    #pragma unroll
    for (int k = 0; k < RK; ++k) {
        float a0 = hs[(4*ty+0)*17+k], a1 = hs[(4*ty+1)*17+k];
        float a2 = hs[(4*ty+2)*17+k], a3 = hs[(4*ty+3)*17+k];
        float w0 = w2s[(4*tx+0)*17+k], w1 = w2s[(4*tx+1)*17+k];
        float w2v = w2s[(4*tx+2)*17+k], w3 = w2s[(4*tx+3)*17+k];
        acc[0][0]=__fmaf_rn(a0,w0,acc[0][0]); acc[0][1]=__fmaf_rn(a0,w1,acc[0][1]);
        acc[0][2]=__fmaf_rn(a0,w2v,acc[0][2]); acc[0][3]=__fmaf_rn(a0,w3,acc[0][3]);
        acc[1][0]=__fmaf_rn(a1,w0,acc[1][0]); acc[1][1]=__fmaf_rn(a1,w1,acc[1][1]);
        acc[1][2]=__fmaf_rn(a1,w2v,acc[1][2]); acc[1][3]=__fmaf_rn(a1,w3,acc[1][3]);
        acc[2][0]=__fmaf_rn(a2,w0,acc[2][0]); acc[2][1]=__fmaf_rn(a2,w1,acc[2][1]);
        acc[2][2]=__fmaf_rn(a2,w2v,acc[2][2]); acc[2][3]=__fmaf_rn(a2,w3,acc[2][3]);
        acc[3][0]=__fmaf_rn(a3,w0,acc[3][0]); acc[3][1]=__fmaf_rn(a3,w1,acc[3][1]);
        acc[3][2]=__fmaf_rn(a3,w2v,acc[3][2]); acc[3][3]=__fmaf_rn(a3,w3,acc[3][3]);
    }

    if (!qk) {   // value field -> bf16 Avb
        #pragma unroll
        for (int i = 0; i < 4; ++i) {
            ushort4 v = make_ushort4(f2bf(acc[i][0]), f2bf(acc[i][1]),
                                     f2bf(acc[i][2]), f2bf(acc[i][3]));
            *(ushort4*)(Avb + (size_t)(s0 + 4*ty + i) * D_ + hh * HD + 4*tx) = v;
        }
        return;
    }

    // stash A values for the projection phase
    #pragma unroll
    for (int i = 0; i < 4; ++i)
        *(float4*)(At + (4*ty + i) * 68 + 4*tx) =
            make_float4(acc[i][0], acc[i][1], acc[i][2], acc[i][3]);

    // raw base copy (q->L[0:64) or k->R[64:128)) — no LDS dependency
    {
        unsigned short* P = which ? R : L;
        const float* src = which ? kb : qb;
        const int segb = which ? 64 : 0;
        int r = t >> 2, cq = (t & 3) * 16;
        const float* sp = src + ((size_t)(hh * S_ + s0 + r)) * HD + cq;
        unsigned short* dp = P + ((size_t)(hh * S_ + s0 + r)) * 384 + segb + cq;
        #pragma unroll
        for (int u = 0; u < 4; ++u) {
            float4 v = *(const float4*)(sp + 4*u);
            *(ushort4*)(dp + 4*u) = make_ushort4(f2bf(v.x), f2bf(v.y), f2bf(v.z), f2bf(v.w));
        }
    }

    // per-dd weights w = relb * g_rel for this head
    float w_[4];
    {
        float grv = g_rel[hh];
        float4 rb4 = *(const float4*)(relb + hh * HD + 4*tx);
        w_[0] = rb4.x * grv; w_[1] = rb4.y * grv; w_[2] = rb4.z * grv; w_[3] = rb4.w * grv;
    }

    // power/poly segments + row-reduction partials
    float red[4];
    #pragma unroll
    for (int i = 0; i < 4; ++i) {
        size_t rb = ((size_t)(hh * S_ + s0 + 4*ty + i)) * 384;
        float partial = 0.f;
        ushort4 o1, o2, o3, o4;
        if (which == 0) {
            #pragma unroll
            for (int j = 0; j < 4; ++j) {
                float xv = acc[i][j];
                float x2 = xv*xv, x3 = x2*xv, x4 = x2*x2, x5 = x3*x2;
                ((unsigned short*)&o1)[j] = f2bf(xv);
                ((unsigned short*)&o2)[j] = f2bf(x2);
                ((unsigned short*)&o3)[j] = f2bf(x3);
                ((unsigned short*)&o4)[j] = f2bf(x4);
                partial += w_[j] * x5;
            }
            *(ushort4*)(L + rb + 128 + 4*tx) = o1;
            *(ushort4*)(L + rb + 192 + 4*tx) = o2;
            *(ushort4*)(L + rb + 256 + 4*tx) = o3;
            *(ushort4*)(L + rb + 320 + 4*tx) = o4;
        } else {
            #pragma unroll
            for (int j = 0; j < 4; ++j) {
                float bv = acc[i][j];
                float b2 = bv*bv, b3 = b2*bv, b4 = b2*b2, b5 = b3*b2;
                float w = w_[j];
                ((unsigned short*)&o1)[j] = f2bf(w * (-1.f - 3.f*C3B*b2 - 5.f*C5B*b4));
                ((unsigned short*)&o2)[j] = f2bf(w * (3.f*C3B*bv + 10.f*C5B*b3));
                ((unsigned short*)&o3)[j] = f2bf(w * (-C3B - 10.f*C5B*b2));
                ((unsigned short*)&o4)[j] = f2bf(w * (5.f*C5B*bv));
                partial += w * (bv + C3B*b3 + C5B*b5);
            }
            *(ushort4*)(R + rb + 128 + 4*tx) = o1;
            *(ushort4*)(R + rb + 192 + 4*tx) = o2;
            *(ushort4*)(R + rb + 256 + 4*tx) = o3;
            *(ushort4*)(R + rb + 320 + 4*tx) = o4;
        }
        red[i] = partial;
    }
    #pragma unroll
    for (int mm = 1; mm < 16; mm <<= 1) {
        #pragma unroll
        for (int i = 0; i < 4; ++i) red[i] += __shfl_xor(red[i], mm);
    }
    if (tx == 0) {
        #pragma unroll
        for (int i = 0; i < 4; ++i) {
            int row = hh * S_ + s0 + 4*ty + i;
            if (which == 0) I[row] = -C5B * red[i];
            else            J[row] = red[i];
        }
    }
    __syncthreads();

    // projection: pacc[s][i] = sum_dd At[s][dd] * W[i][dd]  (then * 0.125*g_attn)
    float pacc[4][4] = {};
    #pragma unroll 8
    for (int dd = 0; dd < HD; ++dd) {
        float a0 = At[(4*ty+0)*68+dd], a1 = At[(4*ty+1)*68+dd];
        float a2 = At[(4*ty+2)*68+dd], a3 = At[(4*ty+3)*68+dd];
        float4 wv = *(const float4*)(Ws + dd*68 + 4*tx);
        pacc[0][0]=__fmaf_rn(a0,wv.x,pacc[0][0]); pacc[0][1]=__fmaf_rn(a0,wv.y,pacc[0][1]);
        pacc[0][2]=__fmaf_rn(a0,wv.z,pacc[0][2]); pacc[0][3]=__fmaf_rn(a0,wv.w,pacc[0][3]);
        pacc[1][0]=__fmaf_rn(a1,wv.x,pacc[1][0]); pacc[1][1]=__fmaf_rn(a1,wv.y,pacc[1][1]);
        pacc[1][2]=__fmaf_rn(a1,wv.z,pacc[1][2]); pacc[1][3]=__fmaf_rn(a1,wv.w,pacc[1][3]);
        pacc[2][0]=__fmaf_rn(a2,wv.x,pacc[2][0]); pacc[2][1]=__fmaf_rn(a2,wv.y,pacc[2][1]);
        pacc[2][2]=__fmaf_rn(a2,wv.z,pacc[2][2]); pacc[2][3]=__fmaf_rn(a2,wv.w,pacc[2][3]);
        pacc[3][0]=__fmaf_rn(a3,wv.x,pacc[3][0]); pacc[3][1]=__fmaf_rn(a3,wv.y,pacc[3][1]);
        pacc[3][2]=__fmaf_rn(a3,wv.z,pacc[3][2]); pacc[3][3]=__fmaf_rn(a3,wv.w,pacc[3][3]);
    }
    float sc = 0.125f * g_attn[hh];
    #pragma unroll
    for (int i = 0; i < 4; ++i) {
        size_t rb = ((size_t)(hh * S_ + s0 + 4*ty + i)) * 384;
        ushort4 o = make_ushort4(f2bf(pacc[i][0]*sc), f2bf(pacc[i][1]*sc),
                                 f2bf(pacc[i][2]*sc), f2bf(pacc[i][3]*sc));
        unsigned short* dst = which ? (R + rb + 4*tx) : (L + rb + 64 + 4*tx);
        *(ushort4*)dst = o;
    }
}

// ---------------- Kernel 3 (merged tail): 96 delta units + 768 mm units.
// Delta units (2x K-depth) at low block indices so they start first and
// their longer loop hides under the mm wave — one launch, no 96-block tail.
__global__ __launch_bounds__(256) void k_tail(
    const unsigned short* __restrict__ Avb, const unsigned short* __restrict__ Wvb,
    const float* __restrict__ g_val,
    const unsigned short* __restrict__ L, const unsigned short* __restrict__ R,
    const float* __restrict__ J, const float* __restrict__ I,
    float* __restrict__ dv, float* __restrict__ gauge)
{
    const int t = threadIdx.x;
    const int wave = t >> 6, lane = t & 63;
    const int wy = wave >> 1, wx = wave & 1;
    const int m = lane & 15, q = lane >> 4;
    const int bid = blockIdx.x;

    if (bid < 96) {
        // ---- dv = tanh(g_val) * (Avb @ Wvb^T), full K=768 ----
        const int e0 = (bid % 12) * 64, s0 = (bid / 12) * 64;
        const int sb = s0 + wy * 32, eb = e0 + wx * 32;

        const unsigned short* pa0 = Avb + (size_t)(sb + m) * D_ + 8 * q;
        const unsigned short* pa1 = pa0 + 16 * D_;
        const unsigned short* pb0 = Wvb + (size_t)(eb + m) * D_ + 8 * q;
        const unsigned short* pb1 = pb0 + 16 * D_;

        ffrag acc00 = {0.f,0.f,0.f,0.f}, acc01 = acc00, acc10 = acc00, acc11 = acc00;
        #pragma unroll 8
        for (int kc = 0; kc < 24; ++kc) {
            bfrag a0 = *(const bfrag*)(pa0 + kc * 32);
            bfrag a1 = *(const bfrag*)(pa1 + kc * 32);
            bfrag b0 = *(const bfrag*)(pb0 + kc * 32);
            bfrag b1 = *(const bfrag*)(pb1 + kc * 32);
            acc00 = __builtin_amdgcn_mfma_f32_16x16x32_bf16(a0, b0, acc00, 0, 0, 0);
            acc01 = __builtin_amdgcn_mfma_f32_16x16x32_bf16(a0, b1, acc01, 0, 0, 0);
            acc10 = __builtin_amdgcn_mfma_f32_16x16x32_bf16(a1, b0, acc10, 0, 0, 0);
            acc11 = __builtin_amdgcn_mfma_f32_16x16x32_bf16(a1, b1, acc11, 0, 0, 0);
        }

        const float t0 = fast_tanh(g_val[eb + m]);
        const float t1 = fast_tanh(g_val[eb + 16 + m]);
        #pragma unroll
        for (int reg = 0; reg < 4; ++reg) {
            int r0 = sb + 4 * q + reg, r1 = r0 + 16;
            dv[(size_t)r0 * D_ + eb + m]      = acc00[reg] * t0;
            dv[(size_t)r0 * D_ + eb + 16 + m] = acc01[reg] * t1;
            dv[(size_t)r1 * D_ + eb + m]      = acc10[reg] * t0;
            dv[(size_t)r1 * D_ + eb + 16 + m] = acc11[reg] * t1;
        }
        return;
    }

    // ---- gauge = L @ R^T (K=384) + J[j] + I[i] ----
    const int u = bid - 96;
    const int h = u >> 6;
    const int rem = u & 63;
    const int i0 = (rem >> 3) * 64, j0 = (rem & 7) * 64;
    const int ib = i0 + wy * 32, jb = j0 + wx * 32;

    const unsigned short* pa0 = L + ((size_t)(h * S_) + ib + m) * 384 + 8 * q;
    const unsigned short* pa1 = pa0 + 16 * 384;
    const unsigned short* pb0 = R + ((size_t)(h * S_) + jb + m) * 384 + 8 * q;
    const unsigned short* pb1 = pb0 + 16 * 384;

    ffrag acc00 = {0.f,0.f,0.f,0.f}, acc01 = acc00, acc10 = acc00, acc11 = acc00;
    #pragma unroll
    for (int kc = 0; kc < 12; ++kc) {
        bfrag a0 = *(const bfrag*)(pa0 + kc * 32);
        bfrag a1 = *(const bfrag*)(pa1 + kc * 32);
        bfrag b0 = *(const bfrag*)(pb0 + kc * 32);
        bfrag b1 = *(const bfrag*)(pb1 + kc * 32);
        acc00 = __builtin_amdgcn_mfma_f32_16x16x32_bf16(a0, b0, acc00, 0, 0, 0);
        acc01 = __builtin_amdgcn_mfma_f32_16x16x32_bf16(a0, b1, acc01, 0, 0, 0);
        acc10 = __builtin_amdgcn_mfma_f32_16x16x32_bf16(a1, b0, acc10, 0, 0, 0);
        acc11 = __builtin_amdgcn_mfma_f32_16x16x32_bf16(a1, b1, acc11, 0, 0, 0);
    }

    const float Jc0 = J[h * S_ + jb + m];
    const float Jc1 = J[h * S_ + jb + 16 + m];
    float* ob = gauge + ((size_t)h * S_) * S_;
    #pragma unroll
    for (int reg = 0; reg < 4; ++reg) {
        int r0 = ib + 4 * q + reg, r1 = r0 + 16;
        float i0v = I[h * S_ + r0];
        ob[(size_t)r0 * S_ + jb + m]      = acc00[reg] + Jc0 + i0v;
        ob[(size_t)r0 * S_ + jb + 16 + m] = acc01[reg] + Jc1 + i0v;
        float i1v = I[h * S_ + r1];
        ob[(size_t)r1 * S_ + jb + m]      = acc10[reg] + Jc0 + i1v;
        ob[(size_t)r1 * S_ + jb + 16 + m] = acc11[reg] + Jc1 + i1v;
    }
}

extern "C" void kernel_launch(void* const* d_in, const int* in_sizes, int n_in,
                              void* d_out, int out_size, void* d_ws, size_t ws_size,
                              hipStream_t stream)
{
    (void)in_sizes; (void)n_in; (void)out_size; (void)ws_size;
    const float* hs   = (const float*)d_in[0];
    const float* qb   = (const float*)d_in[1];
    const float* kb   = (const float*)d_in[2];
    const float* gam  = (const float*)d_in[3];
    const float* bet  = (const float*)d_in[4];
    const float* W1   = (const float*)d_in[5];
    const float* W2   = (const float*)d_in[6];
    const float* Wq   = (const float*)d_in[7];
    const float* Wk   = (const float*)d_in[8];
    const float* Wv   = (const float*)d_in[9];
    const float* relb = (const float*)d_in[10];
    const float* ga   = (const float*)d_in[11];
    const float* gr   = (const float*)d_in[12];
    const float* gv   = (const float*)d_in[13];

    // ws layout
    unsigned short* Avb = (unsigned short*)d_ws;              // 512*768
    unsigned short* Wvb = Avb + (size_t)S_ * D_;              // 768*768
    unsigned short* Lb  = Wvb + (size_t)D_ * D_;              // 12*512*384
    unsigned short* Rb  = Lb + (size_t)NH * S_ * 384;         // 12*512*384
    float* Jv   = (float*)(Rb + (size_t)NH * S_ * 384);       // 12*512
    float* Iv   = Jv + NH * S_;                               // 12*512

    float* gauge = (float*)d_out;                             // 12*512*512
    float* dv   = gauge + (size_t)NH * S_ * S_;               // 512*768
    float* hbuf = dv;                                         // h in dv slot (dead until k_tail)

    k_ln    <<<dim3(512),      dim3(64),  0, stream>>>(hs, gam, bet, W1, Wv, Wvb, hbuf);
    k_amix  <<<dim3(288),      dim3(256), 0, stream>>>(hbuf, W2, Wq, Wk, ga, qb, kb, relb, gr,
                                                       Avb, Lb, Rb, Jv, Iv);
    k_tail  <<<dim3(864),      dim3(256), 0, stream>>>(Avb, Wvb, gv, Lb, Rb, Jv, Iv, dv, gauge);
}

// Round 4
// 127.874 us; speedup vs baseline: 1.5838x; 1.0111x over previous
//
#include <hip/hip_runtime.h>

#define S_ 512
#define D_ 768
#define NH 12
#define HD 64
#define RK 16
#define D3 2304
#define LN_EPS 1e-5f

// odd Taylor tanh coefficients (deg-5; |d|<~0.35)
#define C3B (-0.3333333433f)
#define C5B (0.1333333403f)

typedef __attribute__((ext_vector_type(8))) short bfrag;
typedef __attribute__((ext_vector_type(4))) float ffrag;

__device__ __forceinline__ unsigned short f2bf(float f) {
    unsigned int u = __float_as_uint(f);
    unsigned int r = (u + 0x7FFFu + ((u >> 16) & 1u)) >> 16;   // RNE
    return (unsigned short)r;
}

// Pade [3/4] tanh for g_val (|x|<=0.02)
__device__ __forceinline__ float fast_tanh(float x) {
    float x2 = x * x;
    float num = x * __fmaf_rn(x2, 10.f, 105.f);
    float den = __fmaf_rn(x2 + 45.f, x2, 105.f);
    return num * __builtin_amdgcn_rcpf(den);
}

// ---------------- Kernel 1: LayerNorm + h = silu(xn @ W1^T), one wave/row;
// NOW ALSO: A_v row = silu(h) @ W2v^T -> bf16 Avb (v-units folded in here),
// and Wv -> bf16 pack. 512 blocks x 64 threads. -----------------------------
__global__ __launch_bounds__(64) void k_ln(
    const float* __restrict__ x, const float* __restrict__ gamma,
    const float* __restrict__ beta, const float* __restrict__ W1,
    const float* __restrict__ W2, const float* __restrict__ Wv,
    unsigned short* __restrict__ Wvb, unsigned short* __restrict__ Avb,
    float* __restrict__ hout)
{
    const int row = blockIdx.x;
    const int lane = threadIdx.x;
    const float4* xr = (const float4*)(x + (size_t)row * D_);
    float4 a = xr[lane], b = xr[lane + 64], c = xr[lane + 128];
    float s = a.x + a.y + a.z + a.w + b.x + b.y + b.z + b.w + c.x + c.y + c.z + c.w;
    float sq = a.x*a.x + a.y*a.y + a.z*a.z + a.w*a.w
             + b.x*b.x + b.y*b.y + b.z*b.z + b.w*b.w
             + c.x*c.x + c.y*c.y + c.z*c.z + c.w*c.w;
    #pragma unroll
    for (int m = 1; m < 64; m <<= 1) { s += __shfl_xor(s, m); sq += __shfl_xor(sq, m); }
    float mean = s * (1.f / D_);
    float rstd = rsqrtf(sq * (1.f / D_) - mean * mean + LN_EPS);
    const float4* g4 = (const float4*)gamma;
    const float4* b4 = (const float4*)beta;
    float4 ga_ = g4[lane], gb_ = g4[lane + 64], gc_ = g4[lane + 128];
    float4 ba_ = b4[lane], bb_ = b4[lane + 64], bc_ = b4[lane + 128];
    float4 na, nb, nc;
    na.x = (a.x-mean)*rstd*ga_.x + ba_.x; na.y = (a.y-mean)*rstd*ga_.y + ba_.y;
    na.z = (a.z-mean)*rstd*ga_.z + ba_.z; na.w = (a.w-mean)*rstd*ga_.w + ba_.w;
    nb.x = (b.x-mean)*rstd*gb_.x + bb_.x; nb.y = (b.y-mean)*rstd*gb_.y + bb_.y;
    nb.z = (b.z-mean)*rstd*gb_.z + bb_.z; nb.w = (b.w-mean)*rstd*gb_.w + bb_.w;
    nc.x = (c.x-mean)*rstd*gc_.x + bc_.x; nc.y = (c.y-mean)*rstd*gc_.y + bc_.y;
    nc.z = (c.z-mean)*rstd*gc_.z + bc_.z; nc.w = (c.w-mean)*rstd*gc_.w + bc_.w;

    float hval = 0.f;
    #pragma unroll
    for (int r = 0; r < RK; ++r) {
        const float4* wr = (const float4*)(W1 + (size_t)r * D_);
        float4 wa = wr[lane], wb = wr[lane + 64], wc = wr[lane + 128];
        float p = na.x*wa.x + na.y*wa.y + na.z*wa.z + na.w*wa.w
                + nb.x*wb.x + nb.y*wb.y + nb.z*wb.z + nb.w*wb.w
                + nc.x*wc.x + nc.y*wc.y + nc.z*wc.z + nc.w*wc.w;
        #pragma unroll
        for (int m = 1; m < 64; m <<= 1) p += __shfl_xor(p, m);
        if (lane == r) hval = p;
    }
    // silu on all lanes (only 0..15 meaningful)
    float hs_val = hval * __builtin_amdgcn_rcpf(1.f + __expf(-hval));
    if (lane < RK)
        hout[row * RK + lane] = hs_val;

    // broadcast the 16 silu(h) values to all lanes
    float hr[16];
    #pragma unroll
    for (int r = 0; r < RK; ++r) hr[r] = __shfl(hs_val, r);

    // A_v row: e = lane + 64*j ; dot16 with W2 row (1536+e)
    unsigned short* avrow = Avb + (size_t)row * D_;
    #pragma unroll
    for (int j = 0; j < 12; ++j) {
        const float4* wrow = (const float4*)(W2 + (size_t)(1536 + lane + 64*j) * RK);
        float4 w0 = wrow[0], w1 = wrow[1], w2 = wrow[2], w3 = wrow[3];
        float acc = hr[0]*w0.x + hr[1]*w0.y + hr[2]*w0.z + hr[3]*w0.w
                  + hr[4]*w1.x + hr[5]*w1.y + hr[6]*w1.z + hr[7]*w1.w
                  + hr[8]*w2.x + hr[9]*w2.y + hr[10]*w2.z + hr[11]*w2.w
                  + hr[12]*w3.x + hr[13]*w3.y + hr[14]*w3.z + hr[15]*w3.w;
        avrow[lane + 64*j] = f2bf(acc);
    }

    // Wv -> bf16 pack: 589824 elems / 32768 threads = 18 each
    const int gid = blockIdx.x * 64 + threadIdx.x;
    #pragma unroll
    for (int l = 0; l < 18; ++l)
        Wvb[gid + 32768 * l] = f2bf(Wv[gid + 32768 * l]);
}

// ---------------- Kernel 2: A-slice GEMM (K=16), q/k blocks only (192):
//  q-blocks : L = [q | aqp'' | x | x^2 | x^3 | x^4], I[row] = -C5 sum w x^5
//  k-blocks : R = [akp'' | k | P1..P4],             J[row] = sum w(b+C3b^3+C5b^5)
__global__ __launch_bounds__(256) void k_amix(
    const float* __restrict__ h, const float* __restrict__ W2,
    const float* __restrict__ Wq, const float* __restrict__ Wk,
    const float* __restrict__ g_attn,
    const float* __restrict__ qb, const float* __restrict__ kb,
    const float* __restrict__ relb, const float* __restrict__ g_rel,
    unsigned short* __restrict__ L, unsigned short* __restrict__ R,
    float* __restrict__ J, float* __restrict__ I)
{
    __shared__ float hs[64 * 17];
    __shared__ float w2s[64 * 17];
    __shared__ float At[64 * 68];    // [s][dd]
    __shared__ float Ws[64 * 68];    // [dd][i] transposed
    const int b = blockIdx.x;
    const int t = threadIdx.x;
    const int tx = t & 15, ty = t >> 4;

    const int which = b & 1;
    const int hh = (b >> 1) % NH;
    const int s0 = ((b >> 1) / NH) * 64;
    const int c0 = which * D_ + hh * HD;

    {
        int r = t >> 2, q = (t & 3) * 4;
        float4 hv = *(const float4*)(h + (size_t)(s0 + r) * RK + q);
        hs[r*17+q] = hv.x; hs[r*17+q+1] = hv.y; hs[r*17+q+2] = hv.z; hs[r*17+q+3] = hv.w;
        float4 wv = *(const float4*)(W2 + (size_t)(c0 + r) * RK + q);
        w2s[r*17+q] = wv.x; w2s[r*17+q+1] = wv.y; w2s[r*17+q+2] = wv.z; w2s[r*17+q+3] = wv.w;
    }
    {
        const float* Wsrc = which ? Wk : Wq;
        #pragma unroll
        for (int l = 0; l < 4; ++l) {
            int m = t + 256 * l;
            int i = m >> 4, dq = (m & 15) * 4;
            float4 wv = *(const float4*)(Wsrc + (size_t)i * HD + dq);
            Ws[(dq+0)*68+i] = wv.x; Ws[(dq+1)*68+i] = wv.y;
            Ws[(dq+2)*68+i] = wv.z; Ws[(dq+3)*68+i] = wv.w;
        }
    }
    __syncthreads();

    float acc[4][4] = {};
    #pragma unroll
    for (int k = 0; k < RK; ++k) {
        float a0 = hs[(4*ty+0)*17+k], a1 = hs[(4*ty+1)*17+k];
        float a2 = hs[(4*ty+2)*17+k], a3 = hs[(4*ty+3)*17+k];
        float w0 = w2s[(4*tx+0)*17+k], w1 = w2s[(4*tx+1)*17+k];
        float w2v = w2s[(4*tx+2)*17+k], w3 = w2s[(4*tx+3)*17+k];
        acc[0][0]=__fmaf_rn(a0,w0,acc[0][0]); acc[0][1]=__fmaf_rn(a0,w1,acc[0][1]);
        acc[0][2]=__fmaf_rn(a0,w2v,acc[0][2]); acc[0][3]=__fmaf_rn(a0,w3,acc[0][3]);
        acc[1][0]=__fmaf_rn(a1,w0,acc[1][0]); acc[1][1]=__fmaf_rn(a1,w1,acc[1][1]);
        acc[1][2]=__fmaf_rn(a1,w2v,acc[1][2]); acc[1][3]=__fmaf_rn(a1,w3,acc[1][3]);
        acc[2][0]=__fmaf_rn(a2,w0,acc[2][0]); acc[2][1]=__fmaf_rn(a2,w1,acc[2][1]);
        acc[2][2]=__fmaf_rn(a2,w2v,acc[2][2]); acc[2][3]=__fmaf_rn(a2,w3,acc[2][3]);
        acc[3][0]=__fmaf_rn(a3,w0,acc[3][0]); acc[3][1]=__fmaf_rn(a3,w1,acc[3][1]);
        acc[3][2]=__fmaf_rn(a3,w2v,acc[3][2]); acc[3][3]=__fmaf_rn(a3,w3,acc[3][3]);
    }

    // stash A values for the projection phase
    #pragma unroll
    for (int i = 0; i < 4; ++i)
        *(float4*)(At + (4*ty + i) * 68 + 4*tx) =
            make_float4(acc[i][0], acc[i][1], acc[i][2], acc[i][3]);

    // raw base copy (q->L[0:64) or k->R[64:128)) — no LDS dependency
    {
        unsigned short* P = which ? R : L;
        const float* src = which ? kb : qb;
        const int segb = which ? 64 : 0;
        int r = t >> 2, cq = (t & 3) * 16;
        const float* sp = src + ((size_t)(hh * S_ + s0 + r)) * HD + cq;
        unsigned short* dp = P + ((size_t)(hh * S_ + s0 + r)) * 384 + segb + cq;
        #pragma unroll
        for (int u = 0; u < 4; ++u) {
            float4 v = *(const float4*)(sp + 4*u);
            *(ushort4*)(dp + 4*u) = make_ushort4(f2bf(v.x), f2bf(v.y), f2bf(v.z), f2bf(v.w));
        }
    }

    // per-dd weights w = relb * g_rel for this head
    float w_[4];
    {
        float grv = g_rel[hh];
        float4 rb4 = *(const float4*)(relb + hh * HD + 4*tx);
        w_[0] = rb4.x * grv; w_[1] = rb4.y * grv; w_[2] = rb4.z * grv; w_[3] = rb4.w * grv;
    }

    // power/poly segments + row-reduction partials
    float red[4];
    #pragma unroll
    for (int i = 0; i < 4; ++i) {
        size_t rb = ((size_t)(hh * S_ + s0 + 4*ty + i)) * 384;
        float partial = 0.f;
        ushort4 o1, o2, o3, o4;
        if (which == 0) {
            #pragma unroll
            for (int j = 0; j < 4; ++j) {
                float xv = acc[i][j];
                float x2 = xv*xv, x3 = x2*xv, x4 = x2*x2, x5 = x3*x2;
                ((unsigned short*)&o1)[j] = f2bf(xv);
                ((unsigned short*)&o2)[j] = f2bf(x2);
                ((unsigned short*)&o3)[j] = f2bf(x3);
                ((unsigned short*)&o4)[j] = f2bf(x4);
                partial += w_[j] * x5;
            }
            *(ushort4*)(L + rb + 128 + 4*tx) = o1;
            *(ushort4*)(L + rb + 192 + 4*tx) = o2;
            *(ushort4*)(L + rb + 256 + 4*tx) = o3;
            *(ushort4*)(L + rb + 320 + 4*tx) = o4;
        } else {
            #pragma unroll
            for (int j = 0; j < 4; ++j) {
                float bv = acc[i][j];
                float b2 = bv*bv, b3 = b2*bv, b4 = b2*b2, b5 = b3*b2;
                float w = w_[j];
                ((unsigned short*)&o1)[j] = f2bf(w * (-1.f - 3.f*C3B*b2 - 5.f*C5B*b4));
                ((unsigned short*)&o2)[j] = f2bf(w * (3.f*C3B*bv + 10.f*C5B*b3));
                ((unsigned short*)&o3)[j] = f2bf(w * (-C3B - 10.f*C5B*b2));
                ((unsigned short*)&o4)[j] = f2bf(w * (5.f*C5B*bv));
                partial += w * (bv + C3B*b3 + C5B*b5);
            }
            *(ushort4*)(R + rb + 128 + 4*tx) = o1;
            *(ushort4*)(R + rb + 192 + 4*tx) = o2;
            *(ushort4*)(R + rb + 256 + 4*tx) = o3;
            *(ushort4*)(R + rb + 320 + 4*tx) = o4;
        }
        red[i] = partial;
    }
    #pragma unroll
    for (int mm = 1; mm < 16; mm <<= 1) {
        #pragma unroll
        for (int i = 0; i < 4; ++i) red[i] += __shfl_xor(red[i], mm);
    }
    if (tx == 0) {
        #pragma unroll
        for (int i = 0; i < 4; ++i) {
            int row = hh * S_ + s0 + 4*ty + i;
            if (which == 0) I[row] = -C5B * red[i];
            else            J[row] = red[i];
        }
    }
    __syncthreads();

    // projection: pacc[s][i] = sum_dd At[s][dd] * W[i][dd]  (then * 0.125*g_attn)
    float pacc[4][4] = {};
    #pragma unroll 8
    for (int dd = 0; dd < HD; ++dd) {
        float a0 = At[(4*ty+0)*68+dd], a1 = At[(4*ty+1)*68+dd];
        float a2 = At[(4*ty+2)*68+dd], a3 = At[(4*ty+3)*68+dd];
        float4 wv = *(const float4*)(Ws + dd*68 + 4*tx);
        pacc[0][0]=__fmaf_rn(a0,wv.x,pacc[0][0]); pacc[0][1]=__fmaf_rn(a0,wv.y,pacc[0][1]);
        pacc[0][2]=__fmaf_rn(a0,wv.z,pacc[0][2]); pacc[0][3]=__fmaf_rn(a0,wv.w,pacc[0][3]);
        pacc[1][0]=__fmaf_rn(a1,wv.x,pacc[1][0]); pacc[1][1]=__fmaf_rn(a1,wv.y,pacc[1][1]);
        pacc[1][2]=__fmaf_rn(a1,wv.z,pacc[1][2]); pacc[1][3]=__fmaf_rn(a1,wv.w,pacc[1][3]);
        pacc[2][0]=__fmaf_rn(a2,wv.x,pacc[2][0]); pacc[2][1]=__fmaf_rn(a2,wv.y,pacc[2][1]);
        pacc[2][2]=__fmaf_rn(a2,wv.z,pacc[2][2]); pacc[2][3]=__fmaf_rn(a2,wv.w,pacc[2][3]);
        pacc[3][0]=__fmaf_rn(a3,wv.x,pacc[3][0]); pacc[3][1]=__fmaf_rn(a3,wv.y,pacc[3][1]);
        pacc[3][2]=__fmaf_rn(a3,wv.z,pacc[3][2]); pacc[3][3]=__fmaf_rn(a3,wv.w,pacc[3][3]);
    }
    float sc = 0.125f * g_attn[hh];
    #pragma unroll
    for (int i = 0; i < 4; ++i) {
        size_t rb = ((size_t)(hh * S_ + s0 + 4*ty + i)) * 384;
        ushort4 o = make_ushort4(f2bf(pacc[i][0]*sc), f2bf(pacc[i][1]*sc),
                                 f2bf(pacc[i][2]*sc), f2bf(pacc[i][3]*sc));
        unsigned short* dst = which ? (R + rb + 4*tx) : (L + rb + 64 + 4*tx);
        *(ushort4*)dst = o;
    }
}

// ---------------- Kernel 3 (merged tail):
//  bids [0,192)   : mm units, 128x128 tile per block (each wave 64x64 quad,
//                   16 MFMA per 8 loads — 2x MFMA density, half L2 traffic)
//  bids [192,288) : delta units (64x64, K=768)
__global__ __launch_bounds__(256) void k_tail(
    const unsigned short* __restrict__ Avb, const unsigned short* __restrict__ Wvb,
    const float* __restrict__ g_val,
    const unsigned short* __restrict__ L, const unsigned short* __restrict__ R,
    const float* __restrict__ J, const float* __restrict__ I,
    float* __restrict__ dv, float* __restrict__ gauge)
{
    const int t = threadIdx.x;
    const int wave = t >> 6, lane = t & 63;
    const int m = lane & 15, q = lane >> 4;
    const int bid = blockIdx.x;

    if (bid < 192) {
        // ---- gauge = L @ R^T (K=384) + J[j] + I[i], 128x128 per block ----
        const int h = bid >> 4, rem = bid & 15;
        const int i0 = (rem >> 2) * 128, j0 = (rem & 3) * 128;
        const int ib = i0 + (wave >> 1) * 64, jb = j0 + (wave & 1) * 64;
        const size_t hS = (size_t)h * S_;

        const unsigned short* pa[4];
        const unsigned short* pb[4];
        #pragma unroll
        for (int i = 0; i < 4; ++i) {
            pa[i] = L + (hS + ib + 16*i + m) * 384 + 8*q;
            pb[i] = R + (hS + jb + 16*i + m) * 384 + 8*q;
        }

        ffrag acc[4][4];
        #pragma unroll
        for (int i = 0; i < 4; ++i)
            #pragma unroll
            for (int j = 0; j < 4; ++j)
                acc[i][j] = (ffrag){0.f, 0.f, 0.f, 0.f};

        #pragma unroll 2
        for (int kc = 0; kc < 12; ++kc) {
            bfrag a[4], b[4];
            #pragma unroll
            for (int i = 0; i < 4; ++i) {
                a[i] = *(const bfrag*)(pa[i] + kc * 32);
                b[i] = *(const bfrag*)(pb[i] + kc * 32);
            }
            #pragma unroll
            for (int i = 0; i < 4; ++i)
                #pragma unroll
                for (int j = 0; j < 4; ++j)
                    acc[i][j] = __builtin_amdgcn_mfma_f32_16x16x32_bf16(a[i], b[j], acc[i][j], 0, 0, 0);
        }

        float Jc[4];
        #pragma unroll
        for (int j = 0; j < 4; ++j) Jc[j] = J[hS + jb + 16*j + m];
        float* ob = gauge + hS * S_;
        #pragma unroll
        for (int i = 0; i < 4; ++i) {
            #pragma unroll
            for (int reg = 0; reg < 4; ++reg) {
                const int r = ib + 16*i + 4*q + reg;
                const float iv = I[hS + r];
                float* orow = ob + (size_t)r * S_;
                #pragma unroll
                for (int j = 0; j < 4; ++j)
                    orow[jb + 16*j + m] = acc[i][j][reg] + Jc[j] + iv;
            }
        }
        return;
    }

    // ---- dv = tanh(g_val) * (Avb @ Wvb^T), full K=768, 64x64 per block ----
    const int d = bid - 192;
    const int e0 = (d % 12) * 64, s0 = (d / 12) * 64;
    const int wy = wave >> 1, wx = wave & 1;
    const int sb = s0 + wy * 32, eb = e0 + wx * 32;

    const unsigned short* pa0 = Avb + (size_t)(sb + m) * D_ + 8 * q;
    const unsigned short* pa1 = pa0 + 16 * D_;
    const unsigned short* pb0 = Wvb + (size_t)(eb + m) * D_ + 8 * q;
    const unsigned short* pb1 = pb0 + 16 * D_;

    ffrag acc00 = {0.f,0.f,0.f,0.f}, acc01 = acc00, acc10 = acc00, acc11 = acc00;
    #pragma unroll 8
    for (int kc = 0; kc < 24; ++kc) {
        bfrag a0 = *(const bfrag*)(pa0 + kc * 32);
        bfrag a1 = *(const bfrag*)(pa1 + kc * 32);
        bfrag b0 = *(const bfrag*)(pb0 + kc * 32);
        bfrag b1 = *(const bfrag*)(pb1 + kc * 32);
        acc00 = __builtin_amdgcn_mfma_f32_16x16x32_bf16(a0, b0, acc00, 0, 0, 0);
        acc01 = __builtin_amdgcn_mfma_f32_16x16x32_bf16(a0, b1, acc01, 0, 0, 0);
        acc10 = __builtin_amdgcn_mfma_f32_16x16x32_bf16(a1, b0, acc10, 0, 0, 0);
        acc11 = __builtin_amdgcn_mfma_f32_16x16x32_bf16(a1, b1, acc11, 0, 0, 0);
    }

    const float t0 = fast_tanh(g_val[eb + m]);
    const float t1 = fast_tanh(g_val[eb + 16 + m]);
    #pragma unroll
    for (int reg = 0; reg < 4; ++reg) {
        int r0 = sb + 4 * q + reg, r1 = r0 + 16;
        dv[(size_t)r0 * D_ + eb + m]      = acc00[reg] * t0;
        dv[(size_t)r0 * D_ + eb + 16 + m] = acc01[reg] * t1;
        dv[(size_t)r1 * D_ + eb + m]      = acc10[reg] * t0;
        dv[(size_t)r1 * D_ + eb + 16 + m] = acc11[reg] * t1;
    }
}

extern "C" void kernel_launch(void* const* d_in, const int* in_sizes, int n_in,
                              void* d_out, int out_size, void* d_ws, size_t ws_size,
                              hipStream_t stream)
{
    (void)in_sizes; (void)n_in; (void)out_size; (void)ws_size;
    const float* hs   = (const float*)d_in[0];
    const float* qb   = (const float*)d_in[1];
    const float* kb   = (const float*)d_in[2];
    const float* gam  = (const float*)d_in[3];
    const float* bet  = (const float*)d_in[4];
    const float* W1   = (const float*)d_in[5];
    const float* W2   = (const float*)d_in[6];
    const float* Wq   = (const float*)d_in[7];
    const float* Wk   = (const float*)d_in[8];
    const float* Wv   = (const float*)d_in[9];
    const float* relb = (const float*)d_in[10];
    const float* ga   = (const float*)d_in[11];
    const float* gr   = (const float*)d_in[12];
    const float* gv   = (const float*)d_in[13];

    // ws layout
    unsigned short* Avb = (unsigned short*)d_ws;              // 512*768
    unsigned short* Wvb = Avb + (size_t)S_ * D_;              // 768*768
    unsigned short* Lb  = Wvb + (size_t)D_ * D_;              // 12*512*384
    unsigned short* Rb  = Lb + (size_t)NH * S_ * 384;         // 12*512*384
    float* Jv   = (float*)(Rb + (size_t)NH * S_ * 384);       // 12*512
    float* Iv   = Jv + NH * S_;                               // 12*512

    float* gauge = (float*)d_out;                             // 12*512*512
    float* dv   = gauge + (size_t)NH * S_ * S_;               // 512*768
    float* hbuf = dv;                                         // h in dv slot (dead until k_tail)

    k_ln    <<<dim3(512),      dim3(64),  0, stream>>>(hs, gam, bet, W1, W2, Wv, Wvb, Avb, hbuf);
    k_amix  <<<dim3(192),      dim3(256), 0, stream>>>(hbuf, W2, Wq, Wk, ga, qb, kb, relb, gr,
                                                       Lb, Rb, Jv, Iv);
    k_tail  <<<dim3(288),      dim3(256), 0, stream>>>(Avb, Wvb, gv, Lb, Rb, Jv, Iv, dv, gauge);
}